// Round 6
// baseline (550.107 us; speedup 1.0000x reference)
//
#include <hip/hip_runtime.h>

// RopeAttention: B=2, S=2048, H=2048, NH=16, HD=128, fp32 in/out.
// 6 dispatches: prep (cvt X/Wq/Wk/Wv + rope tables), QKV GEMM (z=3), cvt(Wo),
// rope+repack(V), flash attention (fused RoPE(Q), online softmax, defer-max),
// output GEMM (fp32 out). Peak workspace 93.3 MB (lifetime-scheduled aliases).

#define B_   2
#define S_   2048
#define H_   2048
#define NH_  16
#define HD_  128
#define BS_  4096
#define SCALE_ 0.08838834764831845f            // 1/sqrt(128)
#define SC2_   (SCALE_ * 1.4426950408889634f)  // fold log2(e): softmax in exp2 domain
#define THR2_  11.0f                           // defer-max threshold (log2 units ~ 8 nats)

typedef unsigned short u16;
typedef unsigned int   u32;
typedef __attribute__((ext_vector_type(8))) short bf16x8;
typedef __attribute__((ext_vector_type(4))) float f32x4;

typedef __attribute__((address_space(1))) const u32 gu32;
typedef __attribute__((address_space(3))) u32 lu32;

__device__ __forceinline__ void gll16(const void* g, void* l) {
  __builtin_amdgcn_global_load_lds((gu32*)g, (lu32*)l, 16, 0, 0);
}

__device__ __forceinline__ u16 f2bf(float f) {
  union { float f; u32 u; } v; v.f = f;
  u32 r = v.u + 0x7fffu + ((v.u >> 16) & 1u);
  return (u16)(r >> 16);
}
__device__ __forceinline__ float bf2f(u16 u) {
  union { u32 u; float f; } v; v.u = ((u32)u) << 16;
  return v.f;
}

#if __has_builtin(__builtin_amdgcn_exp2f)
__device__ __forceinline__ float exp2_(float x) { return __builtin_amdgcn_exp2f(x); }
#else
__device__ __forceinline__ float exp2_(float x) { return exp2f(x); }
#endif

// ---------------- prep: cvt X/Wq/Wk/Wv -> bf16, + rope tables ----------------
__global__ __launch_bounds__(256)
void k_prep(const float* __restrict__ X,  const float* __restrict__ Wq,
            const float* __restrict__ Wk, const float* __restrict__ Wv,
            u16* __restrict__ Xb,  u16* __restrict__ Wqb, u16* __restrict__ Wkb,
            u16* __restrict__ Wvb,
            float* __restrict__ cosT, float* __restrict__ sinT)
{
  const int y = blockIdx.y;
  if (y == 4) {                       // rope tables: [S][64]
    const int i = blockIdx.x * 256 + threadIdx.x;
    if (i < S_ * 64) {
      const int s = i >> 6, d = i & 63;
      const float ang = (float)s * powf(10000.0f, -(float)d * (1.0f / 64.0f));
      cosT[i] = cosf(ang);
      sinT[i] = sinf(ang);
    }
    return;
  }
  const float* src; u16* dst; int n;
  if      (y == 0) { src = X;  dst = Xb;  n = 8388608; }
  else if (y == 1) { src = Wq; dst = Wqb; n = 4194304; }
  else if (y == 2) { src = Wk; dst = Wkb; n = 4194304; }
  else             { src = Wv; dst = Wvb; n = 4194304; }
  const int i = (blockIdx.x * 256 + threadIdx.x) * 4;
  if (i < n) {
    float4 v = *(const float4*)(src + i);
    u32 w0 = (u32)f2bf(v.x) | ((u32)f2bf(v.y) << 16);
    u32 w1 = (u32)f2bf(v.z) | ((u32)f2bf(v.w) << 16);
    *(uint2*)(dst + i) = make_uint2(w0, w1);
  }
}

// ---------------- standalone cvt (for Wo, deferred past QKV GEMM) ----------------
__global__ __launch_bounds__(256)
void k_cvt(const float* __restrict__ in, u16* __restrict__ out, int n) {
  const int i = (blockIdx.x * 256 + threadIdx.x) * 4;
  if (i < n) {
    float4 v = *(const float4*)(in + i);
    u32 w0 = (u32)f2bf(v.x) | ((u32)f2bf(v.y) << 16);
    u32 w1 = (u32)f2bf(v.z) | ((u32)f2bf(v.w) << 16);
    *(uint2*)(out + i) = make_uint2(w0, w1);
  }
}

// ---------------- bf16 GEMM: C[M,N] = A[M,K] @ W[N,K]^T (m97 structure) ----------------
// M=4096, N=2048, K=2048 fixed. QKV=1: blockIdx.z selects W/out (bf16 out).
// QKV=0: single W0 -> fp32 out via oF.
template<int QKV>
__global__ __launch_bounds__(256)
void k_gemm(const u16* __restrict__ A,
            const u16* __restrict__ W0, const u16* __restrict__ W1, const u16* __restrict__ W2,
            u16* __restrict__ oB0, u16* __restrict__ oB1, u16* __restrict__ oB2,
            float* __restrict__ oF)
{
  const u16* W;
  u16* outB = nullptr;
  if constexpr (QKV != 0) {
    const int z = blockIdx.z;
    W    = (z == 0) ? W0  : (z == 1) ? W1  : W2;
    outB = (z == 0) ? oB0 : (z == 1) ? oB1 : oB2;
  } else {
    W = W0;
  }
  constexpr int K = H_;
  constexpr int N = H_;

  __shared__ u16 lA[2][128 * 32];
  __shared__ u16 lB[2][128 * 32];
  const int tid  = threadIdx.x;
  const int lane = tid & 63;
  const int wr   = (tid >> 6) >> 1;
  const int wc   = (tid >> 6) & 1;
  const long m0 = (long)blockIdx.y * 128;
  const long n0 = (long)blockIdx.x * 128;
  constexpr int nkt = K >> 5;

  const int  eOff  = tid * 8;
  const int  srow  = eOff >> 5;                  // 0..63
  const int  skc   = eOff & 31;
  const long aBase = (m0 + srow) * (long)K + skc;
  const long bBase = (n0 + srow) * (long)K + skc;

  f32x4 acc[4][4] = {};

#define STAGE_(kt_, buf_) do {                                   \
    long ko = (long)(kt_) * 32;                                  \
    gll16(A + aBase + ko,              &lA[buf_][eOff]);         \
    gll16(A + aBase + 64*(long)K + ko, &lA[buf_][2048 + eOff]);  \
    gll16(W + bBase + ko,              &lB[buf_][eOff]);         \
    gll16(W + bBase + 64*(long)K + ko, &lB[buf_][2048 + eOff]);  \
  } while (0)

  STAGE_(0, 0);
  __syncthreads();

  for (int kt = 0; kt < nkt; ++kt) {
    const int buf = kt & 1;
    if (kt + 1 < nkt) STAGE_(kt + 1, buf ^ 1);
    const int roff = lane & 15;
    const int koff = (lane >> 4) * 8;
    bf16x8 af[4], bfr[4];
#pragma unroll
    for (int m = 0; m < 4; ++m)
      af[m] = *(const bf16x8*)&lA[buf][(wr * 64 + m * 16 + roff) * 32 + koff];
#pragma unroll
    for (int n = 0; n < 4; ++n)
      bfr[n] = *(const bf16x8*)&lB[buf][(wc * 64 + n * 16 + roff) * 32 + koff];
#pragma unroll
    for (int m = 0; m < 4; ++m)
#pragma unroll
      for (int n = 0; n < 4; ++n)
        acc[m][n] = __builtin_amdgcn_mfma_f32_16x16x32_bf16(af[m], bfr[n], acc[m][n], 0, 0, 0);
    __syncthreads();
  }
#undef STAGE_

  const int cr = (lane >> 4) * 4;
  const int cc = lane & 15;
#pragma unroll
  for (int m = 0; m < 4; ++m) {
    const long row0 = m0 + wr * 64 + m * 16 + cr;
#pragma unroll
    for (int n = 0; n < 4; ++n) {
      const long col = n0 + wc * 64 + n * 16 + cc;
#pragma unroll
      for (int r = 0; r < 4; ++r) {
        if constexpr (QKV != 0) outB[(row0 + r) * N + col] = f2bf(acc[m][n][r]);
        else                    oF[(row0 + r) * N + col]   = acc[m][n][r];
      }
    }
  }
}

// ---------------- RoPE(V) + repack to flash layout ----------------
// Vt per (b,h,kt): 8192 elems; elem (k,d) at byte (d>>4)*2048 + (d&15)*128 + ((2k)^((d&7)<<4))
__global__ __launch_bounds__(256)
void k_rope_v_t(const u16* __restrict__ Vb, const float* __restrict__ cosT,
                const float* __restrict__ sinT, u16* __restrict__ Vt)
{
  __shared__ u16 tile[64][130];
  const int tid = threadIdx.x;
  const int kt = blockIdx.x, h = blockIdx.y, b = blockIdx.z;
#pragma unroll
  for (int p = 0; p < 4; ++p) {
    const int k  = p * 16 + (tid >> 4);
    const int d0 = (tid & 15) * 8;
    const long src = ((long)b * S_ + kt * 64 + k) * H_ + h * HD_ + d0;
    bf16x8 v = *(const bf16x8*)(Vb + src);
#pragma unroll
    for (int j = 0; j < 8; ++j) tile[k][d0 + j] = (u16)v[j];
  }
  __syncthreads();
  const long outByte = ((((long)b * NH_ + h) * 32 + kt) * 8192) * 2;
#pragma unroll
  for (int p = 0; p < 4; ++p) {
    const int idx = p * 256 + tid;          // 1024 = 128 d * 8 k-groups
    const int d  = idx >> 3;
    const int k0 = (idx & 7) * 8;
    const int dm = d & 63;
    const float sgn = (d < 64) ? -1.0f : 1.0f;
    bf16x8 ov;
#pragma unroll
    for (int j = 0; j < 8; ++j) {
      const int k = k0 + j;
      const float c  = cosT[(kt * 64 + k) * 64 + dm];
      const float sn = sinT[(kt * 64 + k) * 64 + dm];
      const float x  = bf2f(tile[k][d]);
      const float xp = bf2f(tile[k][d ^ 64]);
      ov[j] = (short)f2bf(x * c + sgn * xp * sn);
    }
    const int m = d & 15;
    const int byteoff = (d >> 4) * 2048 + m * 128 + ((2 * k0) ^ ((m & 7) << 4));
    *(bf16x8*)((char*)Vt + outByte + byteoff) = ov;
  }
}

// ---------------- Flash attention (fused RoPE on Q) ----------------
// grid (qt=32, h=16, b=2), 256 thr (4 waves), wave = 16 q-rows, KVBLK=64.
__global__ __launch_bounds__(256)
void k_flash(const u16* __restrict__ Qb, const u16* __restrict__ Kb,
             const u16* __restrict__ Vt, const float* __restrict__ mask,
             const float* __restrict__ cosT, const float* __restrict__ sinT,
             u16* __restrict__ AO)
{
  __shared__ u16 lK[64 * 128];        // XOR-swizzled rows (baked via global src addr)
  __shared__ u16 lV[64 * 128];        // [8 dt][16 d][64 k] swizzled (pre-swizzled in Vt)
  __shared__ u16 lP[4][16 * 64];      // per-wave P, XOR-swizzled
  const int tid = threadIdx.x, lane = tid & 63, wid = tid >> 6;
  const int qt = blockIdx.x, h = blockIdx.y, b = blockIdx.z;
  const long rowQ0 = (long)b * S_ + qt * 64 + wid * 16;
  const int qlr = (lane >> 4) * 4;

  // ---- load Q fragments + in-register RoPE ----
  bf16x8 qf[4];
  {
    const u16* qp = Qb + (rowQ0 + (lane & 15)) * H_ + h * HD_ + (lane >> 4) * 8;
#pragma unroll
    for (int s = 0; s < 4; ++s) qf[s] = *(const bf16x8*)(qp + s * 32);
    const int pos = qt * 64 + wid * 16 + (lane & 15);
    const float* cR = cosT + (pos << 6);
    const float* sR = sinT + (pos << 6);
#pragma unroll
    for (int s2 = 0; s2 < 2; ++s2) {
      const int dbase = s2 * 32 + (lane >> 4) * 8;
#pragma unroll
      for (int j = 0; j < 8; ++j) {
        const float c  = cR[dbase + j];
        const float sn = sR[dbase + j];
        const float x0 = bf2f((u16)qf[s2][j]);
        const float x1 = bf2f((u16)qf[s2 + 2][j]);
        qf[s2][j]     = (short)f2bf(x0 * c - x1 * sn);
        qf[s2 + 2][j] = (short)f2bf(x1 * c + x0 * sn);
      }
    }
  }

  f32x4 o[8] = {};
  float mrun[4], ssum[4];
#pragma unroll
  for (int r = 0; r < 4; ++r) { mrun[r] = -3.0e38f; ssum[r] = 0.0f; }

  const float* mrow[4];
#pragma unroll
  for (int r = 0; r < 4; ++r)
    mrow[r] = mask + (long)b * S_ * S_ + (long)(qt * 64 + wid * 16 + qlr + r) * S_;

  const long kgBase  = ((long)b * S_) * H_ + h * HD_;
  const long vtBase0 = (((long)b * NH_ + h) * 32) * 8192;
  const int  e0 = tid * 8;
  char* lKc = (char*)lK;
  char* lVc = (char*)lV;
  char* lPc = (char*)lP[wid];

  for (int kt = 0; kt < 32; ++kt) {
    // ---- stage K (swizzle via source addr) and V (linear; Vt pre-swizzled) ----
#pragma unroll
    for (int i = 0; i < 4; ++i) {
      int e   = i * 2048 + e0;
      int row = e >> 7;                             // 0..63
      int gd  = (((e >> 3) & 15) ^ (row & 7)) << 3; // swizzled d column
      gll16(Kb + kgBase + (long)(kt * 64 + row) * H_ + gd, (char*)lK + e * 2);
      gll16(Vt + vtBase0 + (long)kt * 8192 + e,            (char*)lV + e * 2);
    }
    __syncthreads();

    // ---- QK^T ----
    f32x4 sc[4] = {};
#pragma unroll
    for (int s = 0; s < 4; ++s) {
#pragma unroll
      for (int n = 0; n < 4; ++n) {
        const int row  = n * 16 + (lane & 15);
        const int byte = row * 256 + (((s * 64) + ((lane >> 4) * 16)) ^ ((row & 7) << 4));
        bf16x8 kf = *(const bf16x8*)(lKc + byte);
        sc[n] = __builtin_amdgcn_mfma_f32_16x16x32_bf16(qf[s], kf, sc[n], 0, 0, 0);
      }
    }

    // ---- scale*mask, online softmax in exp2 domain, defer-max ----
    const int kc0 = kt * 64;
    float y4[4][4];
#pragma unroll
    for (int r = 0; r < 4; ++r)
#pragma unroll
      for (int n = 0; n < 4; ++n)
        y4[n][r] = sc[n][r] * SC2_ * mrow[r][kc0 + n * 16 + (lane & 15)];

    float tmr[4];
#pragma unroll
    for (int r = 0; r < 4; ++r) {
      float tm = fmaxf(fmaxf(y4[0][r], y4[1][r]), fmaxf(y4[2][r], y4[3][r]));
      tm = fmaxf(tm, __shfl_xor(tm, 1, 64));
      tm = fmaxf(tm, __shfl_xor(tm, 2, 64));
      tm = fmaxf(tm, __shfl_xor(tm, 4, 64));
      tm = fmaxf(tm, __shfl_xor(tm, 8, 64));
      tmr[r] = tm;
    }
    const bool defer = (tmr[0] <= mrun[0] + THR2_) && (tmr[1] <= mrun[1] + THR2_) &&
                       (tmr[2] <= mrun[2] + THR2_) && (tmr[3] <= mrun[3] + THR2_);
    if (!__all(defer)) {
#pragma unroll
      for (int r = 0; r < 4; ++r) {
        const float mnew  = fmaxf(mrun[r], tmr[r]);
        const float alpha = exp2_(mrun[r] - mnew);
        mrun[r] = mnew;
        ssum[r] *= alpha;
#pragma unroll
        for (int df = 0; df < 8; ++df) o[df][r] *= alpha;
      }
    }
#pragma unroll
    for (int r = 0; r < 4; ++r) {
      float rs = 0.0f;
#pragma unroll
      for (int n = 0; n < 4; ++n) { float p = exp2_(y4[n][r] - mrun[r]); y4[n][r] = p; rs += p; }
      rs += __shfl_xor(rs, 1, 64);
      rs += __shfl_xor(rs, 2, 64);
      rs += __shfl_xor(rs, 4, 64);
      rs += __shfl_xor(rs, 8, 64);
      ssum[r] += rs;
    }

    // ---- P -> LDS (per-wave, swizzled) ----
#pragma unroll
    for (int n = 0; n < 4; ++n) {
#pragma unroll
      for (int r = 0; r < 4; ++r) {
        const int q = qlr + r;
        const int byte = q * 128 + (((n * 16 + (lane & 15)) * 2) ^ ((q & 7) << 4));
        *(u16*)(lPc + byte) = f2bf(y4[n][r]);
      }
    }
    asm volatile("s_waitcnt lgkmcnt(0)" ::: "memory");
    __builtin_amdgcn_sched_barrier(0);   // rule #18: keep PV ds_reads below the P ds_writes

    // ---- PV ----
#pragma unroll
    for (int s2 = 0; s2 < 2; ++s2) {
      const int q  = lane & 15;
      const int pb = q * 128 + (((s2 * 64) + ((lane >> 4) * 16)) ^ ((q & 7) << 4));
      bf16x8 pf = *(const bf16x8*)(lPc + pb);
#pragma unroll
      for (int df = 0; df < 8; ++df) {
        const int m  = lane & 15;
        const int vb = df * 2048 + m * 128 + (((s2 * 64) + ((lane >> 4) * 16)) ^ ((m & 7) << 4));
        bf16x8 vf = *(const bf16x8*)(lVc + vb);
        o[df] = __builtin_amdgcn_mfma_f32_16x16x32_bf16(pf, vf, o[df], 0, 0, 0);
      }
    }
    __syncthreads();
  }

  // ---- normalize + write ----
#pragma unroll
  for (int r = 0; r < 4; ++r) {
    const float inv = 1.0f / ssum[r];
    const long orow = (rowQ0 + qlr + r) * H_ + h * HD_;
#pragma unroll
    for (int df = 0; df < 8; ++df)
      AO[orow + df * 16 + (lane & 15)] = f2bf(o[df][r] * inv);
  }
}

// ---------------- host ----------------
extern "C" void kernel_launch(void* const* d_in, const int* in_sizes, int n_in,
                              void* d_out, int out_size, void* d_ws, size_t ws_size,
                              hipStream_t stream)
{
  const float* X    = (const float*)d_in[0];
  const float* mask = (const float*)d_in[1];
  const float* Wq   = (const float*)d_in[2];
  const float* Wk   = (const float*)d_in[3];
  const float* Wv   = (const float*)d_in[4];
  const float* Wo   = (const float*)d_in[5];
  float* out = (float*)d_out;
  char* ws = (char*)d_ws;

  // workspace layout (bytes); peak = 93,323,264 (89 MB). Lifetime-scheduled:
  //   Xb [0,16M)      dead after QKV GEMM  -> AO aliases
  //   Wqb[16M,24M), Wkb[24M,32M) dead after QKV GEMM -> Vt (16M) aliases both
  //   Wvb[32M,40M)    dead after QKV GEMM  -> Wob aliases (cvt'd post-GEMM)
  //   Qb [40M,56M), Kb[56M,72M), Vb[72M,88M) (Vb dead after rope_v)
  //   cosT[88M, +512K), sinT[+512K, +1M)
  u16* Xb    = (u16*)(ws + 0);
  u16* Wqb   = (u16*)(ws + 16777216);
  u16* Wkb   = (u16*)(ws + 25165824);
  u16* Wvb   = (u16*)(ws + 33554432);
  u16* Qb    = (u16*)(ws + 41943040);
  u16* Kb    = (u16*)(ws + 58720256);
  u16* Vb    = (u16*)(ws + 75497472);
  float* cosT = (float*)(ws + 92274688);
  float* sinT = (float*)(ws + 92798976);
  u16* Vt  = Wqb;   // alias: spans Wqb+Wkb (16 MB), both dead after QKV GEMM
  u16* AO  = Xb;    // alias: Xb dead after QKV GEMM
  u16* Wob = Wvb;   // alias: Wvb dead after QKV GEMM; written post-GEMM in stream order

  k_prep<<<dim3(8192, 5), 256, 0, stream>>>(X, Wq, Wk, Wv,
                                            Xb, Wqb, Wkb, Wvb, cosT, sinT);

  k_gemm<1><<<dim3(16, 32, 3), 256, 0, stream>>>(Xb, Wqb, Wkb, Wvb, Qb, Kb, Vb, nullptr);

  k_cvt<<<4096, 256, 0, stream>>>(Wo, Wob, 4194304);

  k_rope_v_t<<<dim3(32, 16, 2), 256, 0, stream>>>(Vb, cosT, sinT, Vt);

  k_flash<<<dim3(32, 16, 2), 256, 0, stream>>>(Qb, Kb, Vt, mask, cosT, sinT, AO);

  // NOTE: out goes in the oF slot (last arg) — QKV=0 writes through oF.
  k_gemm<0><<<dim3(16, 32, 1), 256, 0, stream>>>(AO, Wob, nullptr, nullptr,
                                                 nullptr, nullptr, nullptr, out);
}